// Round 3
// baseline (4684.723 us; speedup 1.0000x reference)
//
#include <hip/hip_runtime.h>
#include <cstdint>
#include <cstddef>

#define V_ 32000
#define E_ 512
#define H_ 1024
#define S_ 512
#define T_ 512
#define G4 4096  // 4*H

typedef unsigned long long u64;

// hardware-approx transcendentals (v_exp_f32 / v_rcp_f32, ~1 ulp)
__device__ __forceinline__ float fexp2(float x) { return __builtin_amdgcn_exp2f(x); }
__device__ __forceinline__ float sigm(float x) {
  return __builtin_amdgcn_rcpf(1.0f + fexp2(x * -1.442695041f));
}
__device__ __forceinline__ float ftanh(float x) {
  return 2.0f * __builtin_amdgcn_rcpf(1.0f + fexp2(x * -2.885390082f)) - 1.0f;
}

// ---------------------------------------------------------------------------
// Xi[t, r] = emb[tok[t]] . Wih[r, :] + b1[r] + b2[r]
// tile 64t x 64r, BK=32, 256 threads, 4x4 micro-tile. K-major LDS (stride 68).
// ---------------------------------------------------------------------------
__global__ __launch_bounds__(256) void xi_gemm(
    const float* __restrict__ emb, const int* __restrict__ tok,
    const float* __restrict__ Wih, const float* __restrict__ b1,
    const float* __restrict__ b2, float* __restrict__ Xi) {
  __shared__ float As[32][68];
  __shared__ float Bs[32][68];
  __shared__ int ids[64];
  const int tid = threadIdx.x;
  const int tx = tid & 15, ty = tid >> 4;
  const int t0 = blockIdx.y * 64, r0 = blockIdx.x * 64;
  if (tid < 64) ids[tid] = tok[t0 + tid];
  __syncthreads();
  const int lrow = tid >> 2;        // 0..63
  const int lk   = (tid & 3) * 8;   // 0,8,16,24
  const long arow = (long)ids[lrow] * E_;
  const long brow = (long)(r0 + lrow) * E_;
  float acc[4][4] = {};
  for (int k0 = 0; k0 < E_; k0 += 32) {
    float4 a0 = *(const float4*)(emb + arow + k0 + lk);
    float4 a1 = *(const float4*)(emb + arow + k0 + lk + 4);
    float4 w0 = *(const float4*)(Wih + brow + k0 + lk);
    float4 w1 = *(const float4*)(Wih + brow + k0 + lk + 4);
    __syncthreads();  // previous compute done before overwriting LDS
    As[lk + 0][lrow] = a0.x; As[lk + 1][lrow] = a0.y; As[lk + 2][lrow] = a0.z; As[lk + 3][lrow] = a0.w;
    As[lk + 4][lrow] = a1.x; As[lk + 5][lrow] = a1.y; As[lk + 6][lrow] = a1.z; As[lk + 7][lrow] = a1.w;
    Bs[lk + 0][lrow] = w0.x; Bs[lk + 1][lrow] = w0.y; Bs[lk + 2][lrow] = w0.z; Bs[lk + 3][lrow] = w0.w;
    Bs[lk + 4][lrow] = w1.x; Bs[lk + 5][lrow] = w1.y; Bs[lk + 6][lrow] = w1.z; Bs[lk + 7][lrow] = w1.w;
    __syncthreads();
#pragma unroll
    for (int kk = 0; kk < 32; ++kk) {
      float4 av = *(const float4*)&As[kk][ty * 4];
      float4 bv = *(const float4*)&Bs[kk][tx * 4];
      float a_[4] = {av.x, av.y, av.z, av.w};
      float b_[4] = {bv.x, bv.y, bv.z, bv.w};
#pragma unroll
      for (int i = 0; i < 4; ++i)
#pragma unroll
        for (int j = 0; j < 4; ++j) acc[i][j] += a_[i] * b_[j];
    }
  }
#pragma unroll
  for (int i = 0; i < 4; ++i) {
    const int t = t0 + ty * 4 + i;
#pragma unroll
    for (int j = 0; j < 4; ++j) {
      const int r = r0 + tx * 4 + j;
      Xi[(size_t)t * G4 + r] = acc[i][j] + b1[r] + b2[r];
    }
  }
}

// ---------------------------------------------------------------------------
// Persistent recurrence v3: 64 WGs x 1024 threads, ONE barrier per step.
//  - wave v owns hidden unit wg*16+v; lane g*16+c dots row g*H+unit over
//    h chunk c (64 elems, weights in 16 VGPR float4s).
//  - sync: thread tid polls ITS OWN tagged pair (detect+fetch = one fabric
//    RT), stages to LDS buffer (s&1). Double-buffered LDS: a thread can only
//    stage s+2 into parity p after its producer consumed all s+1 pairs =>
//    every wave here published s+1 => (lockstep) all step-s reads done.
//  - gates: 4-hop butterfly in 16-lane groups + __shfl gather from lanes
//    0/16/32/48; c,h computed redundantly on all lanes, lane 0 publishes.
// ---------------------------------------------------------------------------
__global__ __launch_bounds__(1024, 4) void lstm_seq(
    const float* __restrict__ Xi_enc, const float* __restrict__ Xi_dec,
    const float* __restrict__ Whh_enc, const float* __restrict__ Whh_dec,
    u64* __restrict__ hpair,   // [2][1024] (tag<<32)|f32bits, memset(0) before launch
    float* __restrict__ hs) {  // [512][1024] decoder hidden states
  __shared__ float h_lds[2][16 * 68 + 4];  // chunk-major, stride 68
  const int tid = threadIdx.x;
  const int wg = blockIdx.x;      // 0..63
  const int wv = tid >> 6;        // wave 0..15 -> unit wg*16+wv
  const int ln = tid & 63;        // lane
  const int g  = ln >> 4;         // gate 0..3 (i,f,g,o)
  const int c  = ln & 15;         // h chunk [c*64, c*64+64)
  const int unit = wg * 16 + wv;
  const int grow = g * H_ + unit; // global Whh row this lane dots
  const int c64 = c * 64;

  float4 w[16];
  {
    const float* wp = Whh_enc + (size_t)grow * H_ + c64;
#pragma unroll
    for (int q = 0; q < 16; ++q) w[q] = *(const float4*)(wp + q * 4);
  }
  const float* Xi = Xi_enc;
  float cstate = 0.f, h_own = 0.f;
  int dead = 0;

  for (int s = 0; s < 1024; ++s) {
    if (s == 512) {  // encoder -> decoder transition
      const float* wp = Whh_dec + (size_t)grow * H_ + c64;
#pragma unroll
      for (int q = 0; q < 16; ++q) w[q] = *(const float4*)(wp + q * 4);
      Xi = Xi_dec;
      cstate = ftanh(h_own);  // dc0 = tanh(enc_h); dh0 = enc_h (in pairs)
    }
    // Xi prefetch (independent of h): one 64B line per 16-row gate cluster
    float xi = 0.f;
    if (c == 0) xi = Xi[(size_t)(s & 511) * G4 + grow];

    // poll OWN pair: detect + fetch in one fabric round-trip
    const u64* pb = hpair + (size_t)(s & 1) * H_;
    const unsigned want = (unsigned)s;
    u64 p;
    {
      int tries = 0;
      for (;;) {
        p = __hip_atomic_load(pb + tid, __ATOMIC_RELAXED, __HIP_MEMORY_SCOPE_AGENT);
        if ((unsigned)(p >> 32) == want || dead) break;
        if (++tries > (1 << 20)) { dead = 1; break; }  // hang safety
        __builtin_amdgcn_s_sleep(1);
      }
    }
    float* buf = h_lds[s & 1];
    buf[(tid >> 6) * 68 + (tid & 63)] = __uint_as_float((unsigned)p);
    __syncthreads();  // the ONLY barrier per step

    float acc = 0.f;
    const float* hb = &buf[c * 68];
#pragma unroll
    for (int q = 0; q < 16; ++q) {
      float4 h4 = *(const float4*)(hb + q * 4);
      acc += w[q].x * h4.x + w[q].y * h4.y + w[q].z * h4.z + w[q].w * h4.w;
    }
    // butterfly within the 16-lane chunk group (lane bits 0..3 = c)
    acc += __shfl_xor(acc, 8, 64);
    acc += __shfl_xor(acc, 4, 64);
    acc += __shfl_xor(acc, 2, 64);
    acc += __shfl_xor(acc, 1, 64);
    float val = acc + xi;  // xi valid on c==0 lanes (0,16,32,48) — only those read below

    float ai = __shfl(val, 0, 64);
    float af = __shfl(val, 16, 64);
    float ag = __shfl(val, 32, 64);
    float ao = __shfl(val, 48, 64);
    float i_ = sigm(ai), f_ = sigm(af), g_ = ftanh(ag), o_ = sigm(ao);
    cstate = f_ * cstate + i_ * g_;       // redundantly on all 64 lanes (consistent)
    float h = o_ * ftanh(cstate);
    h_own = h;
    if (ln == 0) {
      u64 pair = ((u64)(unsigned)(s + 1) << 32) | (u64)__float_as_uint(h);
      __hip_atomic_store(hpair + (size_t)((s + 1) & 1) * H_ + unit, pair,
                         __ATOMIC_RELAXED, __HIP_MEMORY_SCOPE_AGENT);
      if (s >= 512) hs[(size_t)(s - 512) * H_ + unit] = h;
    }
  }
}

// ---------------------------------------------------------------------------
// logits tile GEMM (128t x 128v, BK=32, 8x8 micro) with fused partial
// logsumexp epilogue. Never materializes the [512 x 32000] logits.
// ---------------------------------------------------------------------------
#define PHYS(j) ((j) + (((j) >> 5) << 2))  // +4-word shift per 32-col block (bank spread)

__global__ __launch_bounds__(256) void logits_lse(
    const float* __restrict__ hs, const float* __restrict__ Wout,
    const float* __restrict__ bout, const int* __restrict__ tgt,
    float* __restrict__ pmax, float* __restrict__ psum,
    float* __restrict__ tgtlog) {
  __shared__ float As[32][140];
  __shared__ float Bs[32][140];
  __shared__ float red[128][17];
  __shared__ float Mlds[128];
  __shared__ int tg[128];
  const int tid = threadIdx.x;
  const int tx = tid & 15, ty = tid >> 4;
  const int t0 = blockIdx.y * 128, v0 = blockIdx.x * 128;
  if (tid < 128) tg[tid] = tgt[t0 + tid];
  const int lrow = tid >> 1;        // 0..127
  const int lk   = (tid & 1) * 16;  // 0 or 16
  const float* ap = hs + (size_t)(t0 + lrow) * H_ + lk;
  const float* bp = Wout + (size_t)(v0 + lrow) * H_ + lk;
  const int pl = PHYS(lrow);
  const int aoff = PHYS(ty * 8);
  const int boff = PHYS(tx * 8);
  float acc[8][8] = {};
  for (int k0 = 0; k0 < H_; k0 += 32) {
    float4 a[4], b[4];
#pragma unroll
    for (int q = 0; q < 4; ++q) {
      a[q] = *(const float4*)(ap + k0 + q * 4);
      b[q] = *(const float4*)(bp + k0 + q * 4);
    }
    __syncthreads();
#pragma unroll
    for (int q = 0; q < 4; ++q) {
      As[lk + q * 4 + 0][pl] = a[q].x; As[lk + q * 4 + 1][pl] = a[q].y;
      As[lk + q * 4 + 2][pl] = a[q].z; As[lk + q * 4 + 3][pl] = a[q].w;
      Bs[lk + q * 4 + 0][pl] = b[q].x; Bs[lk + q * 4 + 1][pl] = b[q].y;
      Bs[lk + q * 4 + 2][pl] = b[q].z; Bs[lk + q * 4 + 3][pl] = b[q].w;
    }
    __syncthreads();
#pragma unroll
    for (int kk = 0; kk < 32; ++kk) {
      float av[8], bv[8];
      *(float4*)&av[0] = *(const float4*)&As[kk][aoff];
      *(float4*)&av[4] = *(const float4*)&As[kk][aoff + 4];
      *(float4*)&bv[0] = *(const float4*)&Bs[kk][boff];
      *(float4*)&bv[4] = *(const float4*)&Bs[kk][boff + 4];
#pragma unroll
      for (int i = 0; i < 8; ++i)
#pragma unroll
        for (int j = 0; j < 8; ++j) acc[i][j] += av[i] * bv[j];
    }
  }
  // ---- fused epilogue: bias, row max, row sumexp, target logit ----
  float bv8[8];
#pragma unroll
  for (int j = 0; j < 8; ++j) bv8[j] = bout[v0 + tx * 8 + j];
#pragma unroll
  for (int i = 0; i < 8; ++i) {
    float m = -3.0e38f;
#pragma unroll
    for (int j = 0; j < 8; ++j) {
      acc[i][j] += bv8[j];
      m = fmaxf(m, acc[i][j]);
    }
    red[ty * 8 + i][tx] = m;
  }
  __syncthreads();
  if (tid < 128) {
    float M = -3.0e38f;
#pragma unroll
    for (int x = 0; x < 16; ++x) M = fmaxf(M, red[tid][x]);
    Mlds[tid] = M;
  }
  __syncthreads();
#pragma unroll
  for (int i = 0; i < 8; ++i) {
    float M = Mlds[ty * 8 + i];
    float ssum = 0.f;
#pragma unroll
    for (int j = 0; j < 8; ++j) ssum += expf(acc[i][j] - M);
    red[ty * 8 + i][tx] = ssum;
  }
  __syncthreads();
  if (tid < 128) {
    float S = 0.f;
#pragma unroll
    for (int x = 0; x < 16; ++x) S += red[tid][x];
    pmax[(size_t)(t0 + tid) * 250 + blockIdx.x] = Mlds[tid];
    psum[(size_t)(t0 + tid) * 250 + blockIdx.x] = S;
  }
#pragma unroll
  for (int i = 0; i < 8; ++i) {
    const int t = t0 + ty * 8 + i;
    const int loc = tg[ty * 8 + i] - v0 - tx * 8;
    if (loc >= 0 && loc < 8) {
#pragma unroll
      for (int j = 0; j < 8; ++j)
        if (j == loc) tgtlog[t] = acc[i][j];  // static indexing: no scratch spill
    }
  }
}

// ---------------------------------------------------------------------------
// combine 250 (max, sumexp) partials per row -> loss[t] = lse - logit[target]
// ---------------------------------------------------------------------------
__global__ __launch_bounds__(256) void reduce_loss(
    const float* __restrict__ pmax, const float* __restrict__ psum,
    const float* __restrict__ tgtlog, float* __restrict__ out) {
  __shared__ float sm[256];
  __shared__ float ss[256];
  const int t = blockIdx.x, tid = threadIdx.x;
  float m = -3.0e38f;
  if (tid < 250) m = pmax[(size_t)t * 250 + tid];
  sm[tid] = m;
  __syncthreads();
  for (int s = 128; s > 0; s >>= 1) {
    if (tid < s) sm[tid] = fmaxf(sm[tid], sm[tid + s]);
    __syncthreads();
  }
  const float M = sm[0];
  float sv = 0.f;
  if (tid < 250) sv = psum[(size_t)t * 250 + tid] * expf(m - M);
  ss[tid] = sv;
  __syncthreads();
  for (int s = 128; s > 0; s >>= 1) {
    if (tid < s) ss[tid] += ss[tid + s];
    __syncthreads();
  }
  if (tid == 0) out[t] = M + logf(ss[0]) - tgtlog[t];
}

// ---------------------------------------------------------------------------
extern "C" void kernel_launch(void* const* d_in, const int* in_sizes, int n_in,
                              void* d_out, int out_size, void* d_ws, size_t ws_size,
                              hipStream_t stream) {
  const int*   source    = (const int*)  d_in[0];
  const int*   target    = (const int*)  d_in[1];
  const float* enc_embed = (const float*)d_in[2];
  const float* enc_Wih   = (const float*)d_in[3];
  const float* enc_Whh   = (const float*)d_in[4];
  const float* enc_bih   = (const float*)d_in[5];
  const float* enc_bhh   = (const float*)d_in[6];
  const float* dec_embed = (const float*)d_in[7];
  const float* dec_Wih   = (const float*)d_in[8];
  const float* dec_Whh   = (const float*)d_in[9];
  const float* dec_bih   = (const float*)d_in[10];
  const float* dec_bhh   = (const float*)d_in[11];
  const float* Wout      = (const float*)d_in[12];
  const float* bout      = (const float*)d_in[13];
  float* out = (float*)d_out;

  char* ws = (char*)d_ws;
  float* Xi_enc = (float*)(ws);                    // 512*4096*4 = 8 MB
  float* Xi_dec = (float*)(ws + 8388608);          // 8 MB
  float* hs     = (float*)(ws + 16777216);         // 2 MB
  u64*   hpair  = (u64*)  (ws + 18874368);         // 16 KB
  float* pmax   = (float*)(ws + 18890752);         // 512*250*4 = 500 KB
  float* psum   = (float*)(ws + 19402752);         // 500 KB
  float* tgtlog = (float*)(ws + 19914752);         // 2 KB

  hipMemsetAsync((void*)hpair, 0, 2 * H_ * sizeof(u64), stream);  // h0=0, tag=0
  xi_gemm<<<dim3(64, 8), 256, 0, stream>>>(enc_embed, source, enc_Wih, enc_bih, enc_bhh, Xi_enc);
  xi_gemm<<<dim3(64, 8), 256, 0, stream>>>(dec_embed, target, dec_Wih, dec_bih, dec_bhh, Xi_dec);
  lstm_seq<<<64, 1024, 0, stream>>>(Xi_enc, Xi_dec, enc_Whh, dec_Whh, hpair, hs);
  logits_lse<<<dim3(250, 4), 256, 0, stream>>>(hs, Wout, bout, target, pmax, psum, tgtlog);
  reduce_loss<<<512, 256, 0, stream>>>(pmax, psum, tgtlog, out);
}

// Round 4
// 2647.218 us; speedup vs baseline: 1.7697x; 1.7697x over previous
//
#include <hip/hip_runtime.h>
#include <cstdint>
#include <cstddef>

#define V_ 32000
#define E_ 512
#define H_ 1024
#define S_ 512
#define T_ 512
#define G4 4096  // 4*H

typedef unsigned long long u64;

// hardware-approx transcendentals (v_exp_f32 / v_rcp_f32, ~1 ulp)
__device__ __forceinline__ float fexp2(float x) { return __builtin_amdgcn_exp2f(x); }
__device__ __forceinline__ float sigm(float x) {
  return __builtin_amdgcn_rcpf(1.0f + fexp2(x * -1.442695041f));
}
__device__ __forceinline__ float ftanh(float x) {
  return 2.0f * __builtin_amdgcn_rcpf(1.0f + fexp2(x * -2.885390082f)) - 1.0f;
}

// ---------------------------------------------------------------------------
// Xi[t, r] = emb[tok[t]] . Wih[r, :] + b1[r] + b2[r]
// tile 64t x 64r, BK=32, 256 threads, 4x4 micro-tile. K-major LDS (stride 68).
// ---------------------------------------------------------------------------
__global__ __launch_bounds__(256) void xi_gemm(
    const float* __restrict__ emb, const int* __restrict__ tok,
    const float* __restrict__ Wih, const float* __restrict__ b1,
    const float* __restrict__ b2, float* __restrict__ Xi) {
  __shared__ float As[32][68];
  __shared__ float Bs[32][68];
  __shared__ int ids[64];
  const int tid = threadIdx.x;
  const int tx = tid & 15, ty = tid >> 4;
  const int t0 = blockIdx.y * 64, r0 = blockIdx.x * 64;
  if (tid < 64) ids[tid] = tok[t0 + tid];
  __syncthreads();
  const int lrow = tid >> 2;        // 0..63
  const int lk   = (tid & 3) * 8;   // 0,8,16,24
  const long arow = (long)ids[lrow] * E_;
  const long brow = (long)(r0 + lrow) * E_;
  float acc[4][4] = {};
  for (int k0 = 0; k0 < E_; k0 += 32) {
    float4 a0 = *(const float4*)(emb + arow + k0 + lk);
    float4 a1 = *(const float4*)(emb + arow + k0 + lk + 4);
    float4 w0 = *(const float4*)(Wih + brow + k0 + lk);
    float4 w1 = *(const float4*)(Wih + brow + k0 + lk + 4);
    __syncthreads();  // previous compute done before overwriting LDS
    As[lk + 0][lrow] = a0.x; As[lk + 1][lrow] = a0.y; As[lk + 2][lrow] = a0.z; As[lk + 3][lrow] = a0.w;
    As[lk + 4][lrow] = a1.x; As[lk + 5][lrow] = a1.y; As[lk + 6][lrow] = a1.z; As[lk + 7][lrow] = a1.w;
    Bs[lk + 0][lrow] = w0.x; Bs[lk + 1][lrow] = w0.y; Bs[lk + 2][lrow] = w0.z; Bs[lk + 3][lrow] = w0.w;
    Bs[lk + 4][lrow] = w1.x; Bs[lk + 5][lrow] = w1.y; Bs[lk + 6][lrow] = w1.z; Bs[lk + 7][lrow] = w1.w;
    __syncthreads();
#pragma unroll
    for (int kk = 0; kk < 32; ++kk) {
      float4 av = *(const float4*)&As[kk][ty * 4];
      float4 bv = *(const float4*)&Bs[kk][tx * 4];
      float a_[4] = {av.x, av.y, av.z, av.w};
      float b_[4] = {bv.x, bv.y, bv.z, bv.w};
#pragma unroll
      for (int i = 0; i < 4; ++i)
#pragma unroll
        for (int j = 0; j < 4; ++j) acc[i][j] += a_[i] * b_[j];
    }
  }
#pragma unroll
  for (int i = 0; i < 4; ++i) {
    const int t = t0 + ty * 4 + i;
#pragma unroll
    for (int j = 0; j < 4; ++j) {
      const int r = r0 + tx * 4 + j;
      Xi[(size_t)t * G4 + r] = acc[i][j] + b1[r] + b2[r];
    }
  }
}

// ---------------------------------------------------------------------------
// Persistent recurrence v4: 64 WGs x 1024 threads.
//  - CONSUME (v3 idea, kept): thread tid polls ITS OWN pair; a wave's 64
//    consecutive 8B loads coalesce into one global_load; ballot exit.
//    Detect + fetch = ONE fabric round-trip.
//  - PUBLISH (v2 pattern, restored): per-wave h goes through a 16-slot LDS
//    buffer; after barrier B, wave 0's lanes 0..15 issue ONE coalesced 128B
//    tagged-pair store per WG. (v3's 1024 scattered 8B stores tripled
//    WRITE_SIZE and regressed 1.7x -- store coalescing dominates on the
//    sync path.)
//  - gates: in-wave butterfly; activations computed in PARALLEL on lanes
//    0/16/32/48 (sigm/sigm/tanh/sigm), then broadcast; hardware v_exp/v_rcp.
//  - LDS h double-buffer by step parity; write-after-read safety: wave0 of
//    WG Y can only publish tag s+1 (overwriting parity-q pairs) after Y
//    observed ALL s-tags; X's s-tag was stored (program+barrier order) after
//    X's parity-q reads for s-1 were served. Temporal chain at the
//    coherence point => no overwrite before read. (Passed in v1-v3.)
// ---------------------------------------------------------------------------
__global__ __launch_bounds__(1024, 4) void lstm_seq(
    const float* __restrict__ Xi_enc, const float* __restrict__ Xi_dec,
    const float* __restrict__ Whh_enc, const float* __restrict__ Whh_dec,
    u64* __restrict__ hpair,   // [2][1024] (tag<<32)|f32bits, memset(0) before launch
    float* __restrict__ hs) {  // [512][1024] decoder hidden states
  __shared__ float h_lds[2][16 * 68 + 4];  // chunk-major, stride 68
  __shared__ float gh[16];                 // per-wave h handoff to wave 0
  const int tid = threadIdx.x;
  const int wg = blockIdx.x;      // 0..63
  const int wv = tid >> 6;        // wave 0..15 -> unit wg*16+wv
  const int ln = tid & 63;        // lane
  const int g  = ln >> 4;         // gate 0..3 (i,f,g,o)
  const int c  = ln & 15;         // h chunk [c*64, c*64+64)
  const int unit = wg * 16 + wv;
  const int grow = g * H_ + unit; // global Whh row this lane dots
  const int c64 = c * 64;

  float4 w[16];
  {
    const float* wp = Whh_enc + (size_t)grow * H_ + c64;
#pragma unroll
    for (int q = 0; q < 16; ++q) w[q] = *(const float4*)(wp + q * 4);
  }
  const float* Xi = Xi_enc;
  float cstate = 0.f, h_own = 0.f;  // uniform across the wave
  int dead = 0;

  for (int s = 0; s < 1024; ++s) {
    if (s == 512) {  // encoder -> decoder transition
      const float* wp = Whh_dec + (size_t)grow * H_ + c64;
#pragma unroll
      for (int q = 0; q < 16; ++q) w[q] = *(const float4*)(wp + q * 4);
      Xi = Xi_dec;
      cstate = ftanh(h_own);  // dc0 = tanh(enc_h); dh0 = enc_h (in pairs)
    }
    // Xi prefetch (independent of h): one 64B line per 16-row gate cluster
    float xi = 0.f;
    if (c == 0) xi = Xi[(size_t)(s & 511) * G4 + grow];

    // poll OWN pair: wave's 64 consecutive 8B loads coalesce; ballot exit
    const u64* pb = hpair + (size_t)(s & 1) * H_;
    const unsigned want = (unsigned)s;
    u64 p;
    {
      int tries = 0;
      for (;;) {
        p = __hip_atomic_load(pb + tid, __ATOMIC_RELAXED, __HIP_MEMORY_SCOPE_AGENT);
        bool ok = ((unsigned)(p >> 32) == want);
        if (__ballot(ok) == ~0ull || dead) break;
        if (++tries > (1 << 20)) { dead = 1; break; }  // hang safety
        __builtin_amdgcn_s_sleep(1);
      }
    }
    float* buf = h_lds[s & 1];
    buf[wv * 68 + ln] = __uint_as_float((unsigned)p);  // h[wv*64+ln]
    __syncthreads();  // barrier A: h staged

    float acc = 0.f;
    const float* hb = &buf[c * 68];
#pragma unroll
    for (int q = 0; q < 16; ++q) {
      float4 h4 = *(const float4*)(hb + q * 4);
      acc += w[q].x * h4.x + w[q].y * h4.y + w[q].z * h4.z + w[q].w * h4.w;
    }
    // butterfly within the 16-lane chunk group (lane bits 0..3 = c)
    acc += __shfl_xor(acc, 8, 64);
    acc += __shfl_xor(acc, 4, 64);
    acc += __shfl_xor(acc, 2, 64);
    acc += __shfl_xor(acc, 1, 64);
    float val = acc + xi;  // gate sums live on lanes 0,16,32,48

    // activations in parallel across the 4 gate lanes, then broadcast
    float act = (g == 2) ? ftanh(val) : sigm(val);
    float i_ = __shfl(act, 0, 64);
    float f_ = __shfl(act, 16, 64);
    float g_ = __shfl(act, 32, 64);
    float o_ = __shfl(act, 48, 64);
    cstate = f_ * cstate + i_ * g_;   // uniform on all 64 lanes
    float h = o_ * ftanh(cstate);
    h_own = h;
    if (ln == 0) gh[wv] = h;
    __syncthreads();  // barrier B: all 16 unit-h values in gh[]

    if (wv == 0 && ln < 16) {  // ONE coalesced 128B publish per WG
      float hv = gh[ln];
      const int k = wg * 16 + ln;
      u64 pair = ((u64)(unsigned)(s + 1) << 32) | (u64)__float_as_uint(hv);
      __hip_atomic_store(hpair + (size_t)((s + 1) & 1) * H_ + k, pair,
                         __ATOMIC_RELAXED, __HIP_MEMORY_SCOPE_AGENT);
      if (s >= 512) hs[(size_t)(s - 512) * H_ + k] = hv;  // coalesced 64B
    }
  }
}

// ---------------------------------------------------------------------------
// logits tile GEMM (128t x 128v, BK=32, 8x8 micro) with fused partial
// logsumexp epilogue. Never materializes the [512 x 32000] logits.
// ---------------------------------------------------------------------------
#define PHYS(j) ((j) + (((j) >> 5) << 2))  // +4-word shift per 32-col block (bank spread)

__global__ __launch_bounds__(256) void logits_lse(
    const float* __restrict__ hs, const float* __restrict__ Wout,
    const float* __restrict__ bout, const int* __restrict__ tgt,
    float* __restrict__ pmax, float* __restrict__ psum,
    float* __restrict__ tgtlog) {
  __shared__ float As[32][140];
  __shared__ float Bs[32][140];
  __shared__ float red[128][17];
  __shared__ float Mlds[128];
  __shared__ int tg[128];
  const int tid = threadIdx.x;
  const int tx = tid & 15, ty = tid >> 4;
  const int t0 = blockIdx.y * 128, v0 = blockIdx.x * 128;
  if (tid < 128) tg[tid] = tgt[t0 + tid];
  const int lrow = tid >> 1;        // 0..127
  const int lk   = (tid & 1) * 16;  // 0 or 16
  const float* ap = hs + (size_t)(t0 + lrow) * H_ + lk;
  const float* bp = Wout + (size_t)(v0 + lrow) * H_ + lk;
  const int pl = PHYS(lrow);
  const int aoff = PHYS(ty * 8);
  const int boff = PHYS(tx * 8);
  float acc[8][8] = {};
  for (int k0 = 0; k0 < H_; k0 += 32) {
    float4 a[4], b[4];
#pragma unroll
    for (int q = 0; q < 4; ++q) {
      a[q] = *(const float4*)(ap + k0 + q * 4);
      b[q] = *(const float4*)(bp + k0 + q * 4);
    }
    __syncthreads();
#pragma unroll
    for (int q = 0; q < 4; ++q) {
      As[lk + q * 4 + 0][pl] = a[q].x; As[lk + q * 4 + 1][pl] = a[q].y;
      As[lk + q * 4 + 2][pl] = a[q].z; As[lk + q * 4 + 3][pl] = a[q].w;
      Bs[lk + q * 4 + 0][pl] = b[q].x; Bs[lk + q * 4 + 1][pl] = b[q].y;
      Bs[lk + q * 4 + 2][pl] = b[q].z; Bs[lk + q * 4 + 3][pl] = b[q].w;
    }
    __syncthreads();
#pragma unroll
    for (int kk = 0; kk < 32; ++kk) {
      float av[8], bv[8];
      *(float4*)&av[0] = *(const float4*)&As[kk][aoff];
      *(float4*)&av[4] = *(const float4*)&As[kk][aoff + 4];
      *(float4*)&bv[0] = *(const float4*)&Bs[kk][boff];
      *(float4*)&bv[4] = *(const float4*)&Bs[kk][boff + 4];
#pragma unroll
      for (int i = 0; i < 8; ++i)
#pragma unroll
        for (int j = 0; j < 8; ++j) acc[i][j] += av[i] * bv[j];
    }
  }
  // ---- fused epilogue: bias, row max, row sumexp, target logit ----
  float bv8[8];
#pragma unroll
  for (int j = 0; j < 8; ++j) bv8[j] = bout[v0 + tx * 8 + j];
#pragma unroll
  for (int i = 0; i < 8; ++i) {
    float m = -3.0e38f;
#pragma unroll
    for (int j = 0; j < 8; ++j) {
      acc[i][j] += bv8[j];
      m = fmaxf(m, acc[i][j]);
    }
    red[ty * 8 + i][tx] = m;
  }
  __syncthreads();
  if (tid < 128) {
    float M = -3.0e38f;
#pragma unroll
    for (int x = 0; x < 16; ++x) M = fmaxf(M, red[tid][x]);
    Mlds[tid] = M;
  }
  __syncthreads();
#pragma unroll
  for (int i = 0; i < 8; ++i) {
    float M = Mlds[ty * 8 + i];
    float ssum = 0.f;
#pragma unroll
    for (int j = 0; j < 8; ++j) ssum += expf(acc[i][j] - M);
    red[ty * 8 + i][tx] = ssum;
  }
  __syncthreads();
  if (tid < 128) {
    float S = 0.f;
#pragma unroll
    for (int x = 0; x < 16; ++x) S += red[tid][x];
    pmax[(size_t)(t0 + tid) * 250 + blockIdx.x] = Mlds[tid];
    psum[(size_t)(t0 + tid) * 250 + blockIdx.x] = S;
  }
#pragma unroll
  for (int i = 0; i < 8; ++i) {
    const int t = t0 + ty * 8 + i;
    const int loc = tg[ty * 8 + i] - v0 - tx * 8;
    if (loc >= 0 && loc < 8) {
#pragma unroll
      for (int j = 0; j < 8; ++j)
        if (j == loc) tgtlog[t] = acc[i][j];  // static indexing: no scratch spill
    }
  }
}

// ---------------------------------------------------------------------------
// combine 250 (max, sumexp) partials per row -> loss[t] = lse - logit[target]
// ---------------------------------------------------------------------------
__global__ __launch_bounds__(256) void reduce_loss(
    const float* __restrict__ pmax, const float* __restrict__ psum,
    const float* __restrict__ tgtlog, float* __restrict__ out) {
  __shared__ float sm[256];
  __shared__ float ss[256];
  const int t = blockIdx.x, tid = threadIdx.x;
  float m = -3.0e38f;
  if (tid < 250) m = pmax[(size_t)t * 250 + tid];
  sm[tid] = m;
  __syncthreads();
  for (int s = 128; s > 0; s >>= 1) {
    if (tid < s) sm[tid] = fmaxf(sm[tid], sm[tid + s]);
    __syncthreads();
  }
  const float M = sm[0];
  float sv = 0.f;
  if (tid < 250) sv = psum[(size_t)t * 250 + tid] * expf(m - M);
  ss[tid] = sv;
  __syncthreads();
  for (int s = 128; s > 0; s >>= 1) {
    if (tid < s) ss[tid] += ss[tid + s];
    __syncthreads();
  }
  if (tid == 0) out[t] = M + logf(ss[0]) - tgtlog[t];
}

// ---------------------------------------------------------------------------
extern "C" void kernel_launch(void* const* d_in, const int* in_sizes, int n_in,
                              void* d_out, int out_size, void* d_ws, size_t ws_size,
                              hipStream_t stream) {
  const int*   source    = (const int*)  d_in[0];
  const int*   target    = (const int*)  d_in[1];
  const float* enc_embed = (const float*)d_in[2];
  const float* enc_Wih   = (const float*)d_in[3];
  const float* enc_Whh   = (const float*)d_in[4];
  const float* enc_bih   = (const float*)d_in[5];
  const float* enc_bhh   = (const float*)d_in[6];
  const float* dec_embed = (const float*)d_in[7];
  const float* dec_Wih   = (const float*)d_in[8];
  const float* dec_Whh   = (const float*)d_in[9];
  const float* dec_bih   = (const float*)d_in[10];
  const float* dec_bhh   = (const float*)d_in[11];
  const float* Wout      = (const float*)d_in[12];
  const float* bout      = (const float*)d_in[13];
  float* out = (float*)d_out;

  char* ws = (char*)d_ws;
  float* Xi_enc = (float*)(ws);                    // 512*4096*4 = 8 MB
  float* Xi_dec = (float*)(ws + 8388608);          // 8 MB
  float* hs     = (float*)(ws + 16777216);         // 2 MB
  u64*   hpair  = (u64*)  (ws + 18874368);         // 16 KB
  float* pmax   = (float*)(ws + 18890752);         // 512*250*4 = 500 KB
  float* psum   = (float*)(ws + 19402752);         // 500 KB
  float* tgtlog = (float*)(ws + 19914752);         // 2 KB

  hipMemsetAsync((void*)hpair, 0, 2 * H_ * sizeof(u64), stream);  // h0=0, tag=0
  xi_gemm<<<dim3(64, 8), 256, 0, stream>>>(enc_embed, source, enc_Wih, enc_bih, enc_bhh, Xi_enc);
  xi_gemm<<<dim3(64, 8), 256, 0, stream>>>(dec_embed, target, dec_Wih, dec_bih, dec_bhh, Xi_dec);
  lstm_seq<<<64, 1024, 0, stream>>>(Xi_enc, Xi_dec, enc_Whh, dec_Whh, hpair, hs);
  logits_lse<<<dim3(250, 4), 256, 0, stream>>>(hs, Wout, bout, target, pmax, psum, tgtlog);
  reduce_loss<<<512, 256, 0, stream>>>(pmax, psum, tgtlog, out);
}